// Round 6
// baseline (974.838 us; speedup 1.0000x reference)
//
#include <hip/hip_runtime.h>
#include <hip/hip_bf16.h>

// RSmatching: masked-gather GRU + 2-class softmax head.
// v5: v3's static-gang structure + device-scope (sc0 sc1 / LLC-served) sync.
//  - 8 gangs x 24 members (192 WGs x 384 thr), gang = blockIdx&7 (static;
//    correctness placement-independent: all sync data goes through LLC).
//  - member m owns h-dims [32m,32m+32): 96 W_hh rows in VGPR fragments.
//  - per step: poll 24 flags (global_load sc0 sc1 -> LLC) -> stage H[8][768]
//    (sc0 sc1 loads) -> swizzled LDS -> 24 MFMA/wave -> gates -> publish h
//    slice (sc0 sc1 stores) -> s_waitcnt vmcnt(0) -> flag store (sc0 sc1).
//    NO __threadfence anywhere in the loop (no L2 writeback storms).
//  - watchdog: poll gives up after 2^20 iters (marks gang-dead, keeps
//    publishing) => kernel always terminates.
//  - gemm_xg: xg[k][s][2304] = bf16(seq[s][pos[s][k]]) @ W_ih^T + b_ih.

#define NB 64
#define NS 512
#define ND 768
#define TD 2304
#define NM 24

typedef __attribute__((ext_vector_type(4))) float f32x4;
typedef __attribute__((ext_vector_type(8))) short bf16x8;
typedef __attribute__((ext_vector_type(4))) unsigned int u32x4;

__device__ inline unsigned short f2bf(float f) {
  union { float f; unsigned u; } a; a.f = f;
  unsigned r = a.u + 0x7fff + ((a.u >> 16) & 1);
  return (unsigned short)(r >> 16);
}
__device__ inline float bf2f(unsigned short s) {
  union { unsigned u; float f; } a; a.u = ((unsigned)s) << 16;
  return a.f;
}

// ---- device-scope (LLC-served, L1+L2 bypass) access helpers ----
__device__ inline int load_flag(const int* p) {
  int v;
  asm volatile("global_load_dword %0, %1, off sc0 sc1\n\ts_waitcnt vmcnt(0)"
               : "=v"(v) : "v"(p) : "memory");
  return v;
}
__device__ inline void store_flag(int* p, int v) {
  asm volatile("global_store_dword %0, %1, off sc0 sc1"
               :: "v"(p), "v"(v) : "memory");
}
__device__ inline void store_h16(void* p, u32x4 v) {
  asm volatile("global_store_dwordx4 %0, %1, off sc0 sc1"
               :: "v"(p), "v"(v) : "memory");
}
__device__ inline void load2_h16(const void* p0, const void* p1,
                                 u32x4& a, u32x4& b) {
  asm volatile("global_load_dwordx4 %0, %2, off sc0 sc1\n\t"
               "global_load_dwordx4 %1, %3, off sc0 sc1\n\t"
               "s_waitcnt vmcnt(0)"
               : "=&v"(a), "=&v"(b) : "v"(p0), "v"(p1) : "memory");
}
__device__ inline void waitcnt_vm0() {
  asm volatile("s_waitcnt vmcnt(0)" ::: "memory");
}

// ---------------- fp32 -> bf16 ----------------
__global__ void cvt_f32_bf16(const float* __restrict__ in,
                             unsigned short* __restrict__ out, int n) {
  int i = (blockIdx.x * blockDim.x + threadIdx.x) * 4;
  int stride = gridDim.x * blockDim.x * 4;
  for (; i < n; i += stride) {
    float4 v = *(const float4*)(in + i);
    ushort4 o;
    o.x = f2bf(v.x); o.y = f2bf(v.y); o.z = f2bf(v.z); o.w = f2bf(v.w);
    *(ushort4*)(out + i) = o;
  }
}

// ---------------- compact selected positions ----------------
// ctrl[0..63]=cnt, ctrl[64]=cntmax
__global__ void compact_pos(const int* __restrict__ sot,
                            int* __restrict__ pos, int* __restrict__ ctrl) {
  int b = blockIdx.x, t = threadIdx.x;          // 512 threads
  int m = (sot[b * NS + t] != 0) ? 1 : 0;
  unsigned long long ball = __ballot(m);
  int wid = t >> 6, lane = t & 63;
  __shared__ int wcnt[8];
  int prefix = __popcll(ball & ((1ull << lane) - 1ull));
  if (lane == 63) wcnt[wid] = __popcll(ball);
  __syncthreads();
  int base = 0;
  for (int w = 0; w < wid; ++w) base += wcnt[w];
  if (m) pos[b * NS + base + prefix] = t;
  if (t == 511) {
    int total = base + wcnt[7];
    ctrl[b] = total;
    atomicMax(&ctrl[64], total);
  }
}

// ---------------- xg GEMM: gathered rows -> x-projection ----------------
#define BM 128
#define BN 256
__global__ __launch_bounds__(256) void gemm_xg(
    const float* __restrict__ seq,           // fp32 [64][512][768]
    const int* __restrict__ pos,
    const int* __restrict__ ctrl,
    const unsigned short* __restrict__ Bg,   // W_ih bf16 [2304][768]
    const float* __restrict__ bias,          // b_ih fp32
    unsigned short* __restrict__ C) {        // xg bf16 [32768][2304]
  const int cntmax = ctrl[64];
  const int m0 = blockIdx.x * BM;
  if (m0 >= cntmax * 64) return;
  const int n0 = blockIdx.y * BN;
  __shared__ unsigned short lA[BM * 64];
  __shared__ unsigned short lB[BN * 64];
  const int tid = threadIdx.x;
  const int wid = tid >> 6, lane = tid & 63;
  const int wm = (wid & 1) * 64, wn = (wid >> 1) * 128;

  f32x4 acc[4][8];
#pragma unroll
  for (int i = 0; i < 4; ++i)
#pragma unroll
    for (int j = 0; j < 8; ++j) { f32x4 z = {0.f,0.f,0.f,0.f}; acc[i][j] = z; }

  for (int kt = 0; kt < 12; ++kt) {          // K = 768 = 12*64
    __syncthreads();
#pragma unroll
    for (int c = 0; c < 4; ++c) {
      int idx = c * 256 + tid;
      int r = idx >> 3, ch = idx & 7;
      int gm = m0 + r, ks = gm >> 6, ss = gm & 63;
      float4 v0 = {0,0,0,0}, v1 = {0,0,0,0};
      if (ks < ctrl[ss]) {
        int t = pos[ss * NS + ks];
        const float* src = seq + ((size_t)ss * NS + t) * ND + kt * 64 + ch * 8;
        v0 = *(const float4*)src;
        v1 = *(const float4*)(src + 4);
      }
      uint4 o;
      o.x = f2bf(v0.x) | ((unsigned)f2bf(v0.y) << 16);
      o.y = f2bf(v0.z) | ((unsigned)f2bf(v0.w) << 16);
      o.z = f2bf(v1.x) | ((unsigned)f2bf(v1.y) << 16);
      o.w = f2bf(v1.z) | ((unsigned)f2bf(v1.w) << 16);
      *(uint4*)((char*)lA + r * 128 + ((ch * 16) ^ ((r & 7) << 4))) = o;
    }
#pragma unroll
    for (int c = 0; c < 8; ++c) {
      int idx = c * 256 + tid;
      int r = idx >> 3, ch = idx & 7;
      uint4 v = *(const uint4*)(Bg + (size_t)(n0 + r) * ND + kt * 64 + ch * 8);
      *(uint4*)((char*)lB + r * 128 + ((ch * 16) ^ ((r & 7) << 4))) = v;
    }
    __syncthreads();
#pragma unroll
    for (int kk = 0; kk < 2; ++kk) {
      bf16x8 af[4], bfr[8];
      int kb = kk * 64 + (lane >> 4) * 16;
#pragma unroll
      for (int i = 0; i < 4; ++i) {
        int rowA = wm + i * 16 + (lane & 15);
        af[i] = *(const bf16x8*)((const char*)lA + rowA * 128 + (kb ^ ((rowA & 7) << 4)));
      }
#pragma unroll
      for (int i = 0; i < 8; ++i) {
        int rowB = wn + i * 16 + (lane & 15);
        bfr[i] = *(const bf16x8*)((const char*)lB + rowB * 128 + (kb ^ ((rowB & 7) << 4)));
      }
#pragma unroll
      for (int mi = 0; mi < 4; ++mi)
#pragma unroll
        for (int ni = 0; ni < 8; ++ni)
          acc[mi][ni] = __builtin_amdgcn_mfma_f32_16x16x32_bf16(
              af[mi], bfr[ni], acc[mi][ni], 0, 0, 0);
    }
  }
#pragma unroll
  for (int mi = 0; mi < 4; ++mi)
#pragma unroll
    for (int ni = 0; ni < 8; ++ni) {
      int col = n0 + wn + ni * 16 + (lane & 15);
      float bv = bias[col];
#pragma unroll
      for (int j = 0; j < 4; ++j) {
        int row = m0 + wm + mi * 16 + (lane >> 4) * 4 + j;
        C[(size_t)row * TD + col] = f2bf(acc[mi][ni][j] + bv);
      }
    }
}

// ---------------- gang RNN (LLC-served sync, static gangs) ----------------
__global__ __launch_bounds__(384) void rnn_gang(
    const unsigned short* __restrict__ xg,     // bf16 [512*64][2304]
    const unsigned short* __restrict__ whhb,   // bf16 [2304][768]
    const float* __restrict__ bhh,
    const int* __restrict__ ctrl,
    int* __restrict__ flags,                   // [8][24] padded x16 ints
    unsigned short* __restrict__ Hb,           // bf16 [2][64][768]
    const float* __restrict__ wcls,            // fp32 [2][768]
    float* __restrict__ partial) {             // fp32 [24][64][2]
  const int g  = blockIdx.x & 7;               // gang
  const int m  = blockIdx.x >> 3;              // member 0..23
  const int d0 = m * 32;
  const int t  = threadIdx.x;
  const int w  = t >> 6;
  const int lane = t & 63;
  const int c  = lane & 15;
  const int kg = lane >> 4;

  __shared__ __align__(16) char Hl[8 * 1536];            // 12 KB, swizzled
  __shared__ __align__(16) float hp[8][100];             // padded stride
  __shared__ __align__(16) unsigned short hstage[256];

  // my wave's M-tile W fragments -> registers (96 VGPR)
  const int lr = w * 16 + c;                   // local gate row 0..95
  const int grow = (lr >> 5) * ND + d0 + (lr & 31);
  bf16x8 afr[24];
#pragma unroll
  for (int kt = 0; kt < 24; ++kt)
    afr[kt] = *(const bf16x8*)(whhb + (size_t)grow * ND + kt * 32 + kg * 8);

  const int s  = (t >> 5) & 7;                 // gate-thread sample (t<256)
  const int d  = t & 31;                       // gate-thread dim
  const int sg = g * 8 + s;
  float br = 0.f, bz = 0.f, bn = 0.f, h = 0.f;
  int cnt_s = 0;
  if (t < 256) {
    br = bhh[d0 + d]; bz = bhh[ND + d0 + d]; bn = bhh[2 * ND + d0 + d];
    cnt_s = ctrl[sg];
  }
  int Kg = 0;
  for (int i = 0; i < 8; ++i) Kg = max(Kg, ctrl[g * 8 + i]);
  int* FG = flags + g * NM * 16;
  const int pm = lane < NM ? lane : (lane < 2 * NM ? lane - NM : lane - 2 * NM);

  // zero both parities of my H slice (sc0 sc1), then publish flag=1
  if (t < 32) {
    u32x4 z = {0u, 0u, 0u, 0u};
    store_h16(Hb + ((size_t)(g * 8 + (t >> 2))) * ND + d0 + (t & 3) * 8, z);
    store_h16(Hb + ((size_t)(64 + g * 8 + (t >> 2))) * ND + d0 + (t & 3) * 8, z);
  }
  waitcnt_vm0();
  __syncthreads();
  if (t == 0) store_flag(&FG[m * 16], 1);

  int dead = 0;
  for (int k = 0; k < Kg; ++k) {
    // (A) xg load (plain cached; barrier-independent)
    float xr = 0.f, xz = 0.f, xn = 0.f;
    if (t < 256) {
      const unsigned short* xrow = xg + ((size_t)k * 64 + sg) * TD + d0 + d;
      xr = bf2f(xrow[0]); xz = bf2f(xrow[ND]); xn = bf2f(xrow[2 * ND]);
    }
    // (B) poll gang flags (sc0 sc1 -> LLC) with one-shot watchdog
    if (w == 0 && !dead) {
      const int* fp = &FG[pm * 16];
      int spins = 0;
      while (true) {
        int v = load_flag(fp);
        if (__all(v >= k + 1)) break;
        if (++spins > (1 << 20)) { dead = 1; break; }
      }
    }
    __syncthreads();
    // (C) stage H[8][768] -> swizzled LDS (sc0 sc1 loads)
    {
      const unsigned short* hsrc = Hb + ((size_t)(k & 1) * 64 + g * 8) * ND;
      int i1 = t + 384;
      int r0 = t / 96, c0 = t - r0 * 96;
      int r1 = i1 / 96, c1 = i1 - r1 * 96;
      u32x4 a0, a1;
      load2_h16(hsrc + r0 * ND + c0 * 8, hsrc + r1 * ND + c1 * 8, a0, a1);
      *(u32x4*)(Hl + r0 * 1536 + ((c0 * 16) ^ ((r0 & 7) << 4))) = a0;
      *(u32x4*)(Hl + r1 * 1536 + ((c1 * 16) ^ ((r1 & 7) << 4))) = a1;
    }
    __syncthreads();
    // (D) MFMA: hp[96 rows][8 samples] for my tile
    f32x4 acc = {0.f, 0.f, 0.f, 0.f};
#pragma unroll
    for (int kt = 0; kt < 24; ++kt) {
      bf16x8 bfr = *(const bf16x8*)(Hl + (c & 7) * 1536 +
                    ((kt * 64 + kg * 16) ^ ((c & 7) << 4)));
      acc = __builtin_amdgcn_mfma_f32_16x16x32_bf16(afr[kt], bfr, acc, 0, 0, 0);
    }
    if (c < 8) *(f32x4*)&hp[c][w * 16 + kg * 4] = acc;
    __syncthreads();
    // (E) gates; h lives in gate-thread registers
    if (t < 256) {
      float ar = hp[s][d]      + br;
      float az = hp[s][32 + d] + bz;
      float an = hp[s][64 + d] + bn;
      float r  = 1.f / (1.f + __expf(-(xr + ar)));
      float z  = 1.f / (1.f + __expf(-(xz + az)));
      float nn = tanhf(xn + r * an);
      float hn = (1.f - z) * nn + z * h;
      if (k < cnt_s) h = hn;
      hstage[(s << 5) | d] = f2bf(h);
    }
    __syncthreads();
    // (F) publish h slice (sc0 sc1) + vmcnt(0) + flag
    if (t < 32) {
      u32x4 q = *(const u32x4*)((const char*)hstage + (t >> 2) * 64 + (t & 3) * 16);
      store_h16(Hb + ((size_t)((k + 1) & 1) * 64 + g * 8 + (t >> 2)) * ND + d0 + (t & 3) * 8, q);
    }
    waitcnt_vm0();
    if (t == 0) store_flag(&FG[m * 16], k + 2);
  }

  // classifier partials over my 32 dims
  if (t < 256) {
    float p0 = h * wcls[d0 + d];
    float p1 = h * wcls[ND + d0 + d];
#pragma unroll
    for (int off = 16; off; off >>= 1) {
      p0 += __shfl_xor(p0, off);
      p1 += __shfl_xor(p1, off);
    }
    if (d == 0) {
      partial[(size_t)(m * 64 + sg) * 2]     = p0;
      partial[(size_t)(m * 64 + sg) * 2 + 1] = p1;
    }
  }
}

// ---------------- finalize: sum partials + softmax ----------------
__global__ void finalize(const float* __restrict__ partial,
                         const float* __restrict__ bcls,
                         float* __restrict__ out) {
  int s = threadIdx.x;                         // 64
  float l0 = bcls[0], l1 = bcls[1];
  for (int m = 0; m < NM; ++m) {
    l0 += partial[(size_t)(m * 64 + s) * 2];
    l1 += partial[(size_t)(m * 64 + s) * 2 + 1];
  }
  float mx = fmaxf(l0, l1);
  float e0 = __expf(l0 - mx), e1 = __expf(l1 - mx);
  float inv = 1.f / (e0 + e1);
  out[2 * s]     = e0 * inv;
  out[2 * s + 1] = e1 * inv;
}

extern "C" void kernel_launch(void* const* d_in, const int* in_sizes, int n_in,
                              void* d_out, int out_size, void* d_ws, size_t ws_size,
                              hipStream_t stream) {
  const float* seq  = (const float*)d_in[0];
  const int*   sot  = (const int*)d_in[1];
  const float* Wih  = (const float*)d_in[2];
  const float* Whh  = (const float*)d_in[3];
  const float* bih  = (const float*)d_in[4];
  const float* bhh  = (const float*)d_in[5];
  const float* Wcls = (const float*)d_in[6];
  const float* bcls = (const float*)d_in[7];
  float* out = (float*)d_out;

  char* ws = (char*)d_ws;
  unsigned short* xg   = (unsigned short*)(ws);                   // 150,994,944
  unsigned short* wihb = (unsigned short*)(ws + 150994944);       // +3,538,944
  unsigned short* whhb = (unsigned short*)(ws + 154533888);       // +3,538,944
  int*            pos  = (int*)(ws + 158072832);                  // +131,072
  int*            ctrl = (int*)(ws + 158203904);                  // +512
  int*            flg  = (int*)(ws + 158204416);                  // +12,288
  unsigned short* Hb   = (unsigned short*)(ws + 158216704);       // +196,608
  float*          part = (float*)(ws + 158413312);                // +12,288

  cvt_f32_bf16<<<1728, 256, 0, stream>>>(Wih, wihb, TD * ND);
  cvt_f32_bf16<<<1728, 256, 0, stream>>>(Whh, whhb, TD * ND);
  hipMemsetAsync(ctrl, 0, 512 + 12288, stream);   // ctrl + flags
  compact_pos<<<NB, NS, 0, stream>>>(sot, pos, ctrl);
  gemm_xg<<<dim3(NB * NS / BM, TD / BN), 256, 0, stream>>>(seq, pos, ctrl, wihb, bih, xg);
  rnn_gang<<<192, 384, 0, stream>>>(xg, whhb, bhh, ctrl, flg, Hb, Wcls, part);
  finalize<<<1, 64, 0, stream>>>(part, bcls, out);
}